// Round 8
// baseline (12368.604 us; speedup 1.0000x reference)
//
#include <hip/hip_runtime.h>

#define BB 32
#define NN 16384
#define CC 64
#define NC 4096
#define T  1024          // threads per FPS block
#define SLOTS 16         // points per thread
#define PAIRS (SLOTS/2)  // float2 pairs per coord

typedef float f2 __attribute__((ext_vector_type(2)));

// ---------------------------------------------------------------------------
// FPS kernel: one block per batch element. Points + running dists in regs as
// float2 pairs -> v_pk_{add,mul,fma}_f32 packed FP32 (2 pts / 2-cycle issue),
// which also forces arch-VGPR allocation (VOP3P can't read AGPRs; R7 profile
// showed the state living in AGPRs with accvgpr_read/write on every access).
// Distance chain B1 = fma(dz,dz, fma(dx,dx, dy*dy)) — verified bitwise
// (R6 pass, absmax 0.0). elementwise_fma == fmaf bitwise; elementwise_min ==
// fminf; vector -/ * under contract(off) == IEEE sub/mul. Update loop is pure
// dist math; block argmax = value-only reduce + post-hoc rescan + atomicMin
// (first-occurrence ties == numpy argmax).
// ---------------------------------------------------------------------------
__global__ __launch_bounds__(T, 4) void fps_kernel(const float* __restrict__ in,
                                                   float* __restrict__ out) {
#pragma clang fp contract(off)
    const int b    = blockIdx.x;
    const int t    = threadIdx.x;
    const int wave = t >> 6;
    const int lane = t & 63;

    __shared__ float s_wmax[16];
    __shared__ float s_cx, s_cy, s_cz;
    __shared__ int   s_far2[2];

    const float* base = in + (size_t)b * NN * CC;

    f2 px[PAIRS], py[PAIRS], pz[PAIRS], dist[PAIRS];
#pragma unroll
    for (int k = 0; k < PAIRS; ++k) {
        const int i0 = (2 * k) * T + t;
        const int i1 = (2 * k + 1) * T + t;
        const float4 v0 = *reinterpret_cast<const float4*>(base + (size_t)i0 * CC);
        const float4 v1 = *reinterpret_cast<const float4*>(base + (size_t)i1 * CC);
        px[k] = f2{v0.x, v1.x};
        py[k] = f2{v0.y, v1.y};
        pz[k] = f2{v0.z, v1.z};
        dist[k] = f2{1e10f, 1e10f};
    }
    if (t == 0) { s_far2[0] = 0x7fffffff; s_far2[1] = 0x7fffffff; }

    // initial centroid = point 0 (uniform broadcast load)
    float cx = base[0], cy = base[1], cz = base[2];
    int   far = 0;
    __syncthreads();

    int* idx_out = reinterpret_cast<int*>(out);

    for (int it = 0; it < NC; ++it) {
        if (t == 0) idx_out[((size_t)b * NC + it) * CC] = far;
        if (it == NC - 1) break;

        // ---- dist update: packed fp32, no argmax bookkeeping ----
        const f2 cx2 = f2{cx, cx}, cy2 = f2{cy, cy}, cz2 = f2{cz, cz};
#pragma unroll
        for (int k = 0; k < PAIRS; ++k) {
            const f2 dx = px[k] - cx2;                 // v_pk_add (neg mod)
            const f2 dy = py[k] - cy2;
            const f2 dz = pz[k] - cz2;
            const f2 d  = __builtin_elementwise_fma(dz, dz,
                            __builtin_elementwise_fma(dx, dx, dy * dy)); // chain B1
            dist[k] = __builtin_elementwise_min(dist[k], d);             // fminf
        }

        // ---- separate max pass (max3-fusable triples) ----
        const float g0 = fmaxf(fmaxf(dist[0].x, dist[0].y), dist[1].x);
        const float g1 = fmaxf(fmaxf(dist[1].y, dist[2].x), dist[2].y);
        const float g2 = fmaxf(fmaxf(dist[3].x, dist[3].y), dist[4].x);
        const float g3 = fmaxf(fmaxf(dist[4].y, dist[5].x), dist[5].y);
        const float g4 = fmaxf(fmaxf(dist[6].x, dist[6].y), dist[7].x);
        const float h0 = fmaxf(fmaxf(g0, g1), g2);
        const float lv = fmaxf(fmaxf(g3, g4), fmaxf(h0, dist[7].y));

        // ---- wave64 value-max reduce ----
        float wv = lv;
#pragma unroll
        for (int off = 32; off > 0; off >>= 1)
            wv = fmaxf(wv, __shfl_down(wv, off));
        if (lane == 0) s_wmax[wave] = wv;
        if (t == 0) s_far2[(it + 1) & 1] = 0x7fffffff;   // prep next parity buffer
        __syncthreads();                                  // A

        // ---- redundant all-thread block max (broadcast LDS reads) ----
        const float m0 = fmaxf(fmaxf(s_wmax[0],  s_wmax[1]),  fmaxf(s_wmax[2],  s_wmax[3]));
        const float m1 = fmaxf(fmaxf(s_wmax[4],  s_wmax[5]),  fmaxf(s_wmax[6],  s_wmax[7]));
        const float m2 = fmaxf(fmaxf(s_wmax[8],  s_wmax[9]),  fmaxf(s_wmax[10], s_wmax[11]));
        const float m3 = fmaxf(fmaxf(s_wmax[12], s_wmax[13]), fmaxf(s_wmax[14], s_wmax[15]));
        const float gmax = fmaxf(fmaxf(m0, m1), fmaxf(m2, m3));

        // ---- matching threads find first local index, atomicMin for global ----
        if (lv == gmax) {
            int myi = 0x7fffffff;
#pragma unroll
            for (int j = SLOTS - 1; j >= 0; --j) {       // descending: keep smallest j
                const float dj = (j & 1) ? dist[j >> 1].y : dist[j >> 1].x;
                myi = (dj == gmax) ? (j * T + t) : myi;
            }
            atomicMin(&s_far2[it & 1], myi);
        }
        __syncthreads();                                  // B

        far = s_far2[it & 1];

        // ---- owner thread publishes next centroid coords ----
        if ((far & (T - 1)) == t) {
            const int jj = far >> 10;                     // slot 0..15
            float x = px[0].x, y = py[0].x, z = pz[0].x;
#pragma unroll
            for (int k = 1; k < SLOTS; ++k) {
                const bool c = (jj == k);
                const float sx = (k & 1) ? px[k >> 1].y : px[k >> 1].x;
                const float sy = (k & 1) ? py[k >> 1].y : py[k >> 1].x;
                const float sz = (k & 1) ? pz[k >> 1].y : pz[k >> 1].x;
                x = c ? sx : x;
                y = c ? sy : y;
                z = c ? sz : z;
            }
            s_cx = x; s_cy = y; s_cz = z;
        }
        __syncthreads();                                  // C
        cx = s_cx; cy = s_cy; cz = s_cz;
    }
}

// ---------------------------------------------------------------------------
// Gather kernel: one wave64 per output row (64 channels). Reads the stored
// index (int at channel 0 of the row), then copies the full input row.
// ---------------------------------------------------------------------------
__global__ __launch_bounds__(256) void gather_kernel(const float* __restrict__ in,
                                                     float* out) {
    const int gid  = blockIdx.x * blockDim.x + threadIdx.x;
    const int row  = gid >> 6;     // 0 .. B*NC-1
    const int lane = gid & 63;     // channel
    const int b = row >> 12;       // NC == 4096
    const int idx = reinterpret_cast<const int*>(out)[(size_t)row * CC];
    const float v = in[((size_t)b * NN + idx) * CC + lane];
    out[(size_t)row * CC + lane] = v;
}

extern "C" void kernel_launch(void* const* d_in, const int* in_sizes, int n_in,
                              void* d_out, int out_size, void* d_ws, size_t ws_size,
                              hipStream_t stream) {
    const float* in = (const float*)d_in[0];
    float* out = (float*)d_out;

    fps_kernel<<<BB, T, 0, stream>>>(in, out);

    const int total = BB * NC * CC;          // 8,388,608
    gather_kernel<<<total / 256, 256, 0, stream>>>(in, out);
}